// Round 7
// baseline (144.110 us; speedup 1.0000x reference)
//
#include <hip/hip_runtime.h>

#define AS1 __attribute__((address_space(1)))
#define AS3 __attribute__((address_space(3)))

typedef __bf16 bf16x8 __attribute__((ext_vector_type(8)));
typedef float f32x4 __attribute__((ext_vector_type(4)));

// round-to-nearest-even f32 -> bf16
__device__ __forceinline__ unsigned short f2bf(float f) {
  union { float f; unsigned u; } v; v.f = f;
  unsigned u = v.u;
  unsigned r = (u + 0x7fffu + ((u >> 16) & 1u)) >> 16;
  return (unsigned short)r;
}

// ---------------------------------------------------------------------------
// dcalc stage A: partial[is][b][o] = sum_{i in chunk is} ysq[b,i] * W[i,o]^2
// ---------------------------------------------------------------------------
__global__ __launch_bounds__(256) void dcalc_a_kernel(const float* __restrict__ y,
                                                      const float* __restrict__ W,
                                                      float* __restrict__ partial) {
  __shared__ float ysq[32][32];  // [i_local][b]
  const int o = blockIdx.x * 256 + threadIdx.x;
  const int i0 = blockIdx.y * 32;
  for (int e = threadIdx.x; e < 1024; e += 256) {
    int il = e >> 5, b = e & 31;
    float t = y[b * 1024 + i0 + il] * 0.03125f;
    ysq[il][b] = t * t;
  }
  __syncthreads();

  f32x4 acc[8] = {};
#pragma unroll
  for (int il = 0; il < 32; ++il) {
    float w = W[(size_t)(i0 + il) * 1024 + o];
    float w2 = w * w;
#pragma unroll
    for (int b4 = 0; b4 < 8; ++b4) {
      f32x4 q = *(const f32x4*)&ysq[il][b4 * 4];
#pragma unroll
      for (int k = 0; k < 4; ++k) acc[b4][k] = fmaf(q[k], w2, acc[b4][k]);
    }
  }
  float* p = partial + (size_t)blockIdx.y * 32768 + o;
#pragma unroll
  for (int b4 = 0; b4 < 8; ++b4)
#pragma unroll
    for (int k = 0; k < 4; ++k) p[(b4 * 4 + k) * 1024] = acc[b4][k];
}

// ---------------------------------------------------------------------------
// dcalc stage B: dmod[b,o] = rsqrt( sum_is partial[is][b][o] + 1e-8 )
// ---------------------------------------------------------------------------
__global__ __launch_bounds__(256) void dcalc_b_kernel(const float* __restrict__ partial,
                                                      float* __restrict__ dmod) {
  const int bo = blockIdx.x * 256 + threadIdx.x;
  float acc = 0.f;
#pragma unroll 8
  for (int is = 0; is < 32; ++is) acc += partial[(size_t)is * 32768 + bo];
  dmod[bo] = rsqrtf(acc + 1e-8f);
}

// ---------------------------------------------------------------------------
// WT[o,i] = bf16(W[i,o])
// ---------------------------------------------------------------------------
__global__ void wconv_kernel(const float* __restrict__ W,
                             unsigned short* __restrict__ WT) {
  __shared__ float t[32][33];
  const int tx = threadIdx.x;
  const int ty = threadIdx.y;
  const int i0 = blockIdx.y * 32;
  const int o0 = blockIdx.x * 32;
#pragma unroll
  for (int k = 0; k < 4; ++k)
    t[ty + k * 8][tx] = W[(size_t)(i0 + ty + k * 8) * 1024 + o0 + tx];
  __syncthreads();
#pragma unroll
  for (int k = 0; k < 4; ++k)
    WT[(size_t)(o0 + ty + k * 8) * 1024 + i0 + tx] = f2bf(t[tx][ty + k * 8]);
}

// ---------------------------------------------------------------------------
// X[m,i] = bf16(Efou[m,i] * y[b,i]/32)
// ---------------------------------------------------------------------------
__global__ __launch_bounds__(256) void xconv_kernel(const float4* __restrict__ E4,
                                                    const float* __restrict__ y,
                                                    unsigned short* __restrict__ X) {
  const size_t total = (size_t)8388608;  // 32*1024*1024/4
  for (size_t g = (size_t)blockIdx.x * blockDim.x + threadIdx.x; g < total;
       g += (size_t)gridDim.x * blockDim.x) {
    float4 v = E4[g];
    size_t e = g * 4;
    int i = (int)(e & 1023);
    int b = (int)(e >> 20);
    float4 yv = *(const float4*)(y + b * 1024 + i);
    ushort4 o;
    o.x = f2bf(v.x * yv.x * 0.03125f);
    o.y = f2bf(v.y * yv.y * 0.03125f);
    o.z = f2bf(v.z * yv.z * 0.03125f);
    o.w = f2bf(v.w * yv.w * 0.03125f);
    *(ushort4*)(X + e) = o;
  }
}

// ---------------------------------------------------------------------------
// Persistent GEMM: grid 256 (1 block/CU). Each block: output tiles
// (bm, 2p) then (bm, 2p+1) as 32 virtual K-tiles; pipeline runs straight
// through the pair boundary. Operand-swapped MFMA -> lane acc = 4 consecutive
// o -> dwordx4 epilogue stores. B-frags held in regs (read once per K-tile).
// Counted vmcnt: ONE VM(4) per tile. XOR-swizzled LDS, XCD swizzle, setprio.
// ---------------------------------------------------------------------------
#define LDS_TILE 65536  // per-buffer: A 32KB + B 32KB

#define BAR __builtin_amdgcn_s_barrier()
#define LGKM0 asm volatile("s_waitcnt lgkmcnt(0)" ::: "memory")
#define VM(n) asm volatile("s_waitcnt vmcnt(" #n ")" ::: "memory")
#define SCHB __builtin_amdgcn_sched_barrier(0)
#define PRIO(x) __builtin_amdgcn_s_setprio(x)

#define STG_A(r, kt, dst)                                                    \
  __builtin_amdgcn_global_load_lds(                                          \
      (const AS1 void*)(Xs + (size_t)(r) * 64 * 2048 + (kt) * 128),          \
      (AS3 void*)((dst) + (r) * 8192 + sldso), 16, 0, 0)
#define STG_B(r, kt, dst, WsB)                                               \
  __builtin_amdgcn_global_load_lds(                                          \
      (const AS1 void*)((WsB) + (size_t)(r) * 64 * 2048 + (kt) * 128),       \
      (AS3 void*)((dst) + 32768 + (r) * 8192 + sldso), 16, 0, 0)

// swizzled fragment reads (row&7 == l15&7 for all frags)
#define RD_A(mh, mi, kk)                                                     \
  (*(const bf16x8*)(Ab + (wr * 128 + ((mh) * 4 + (mi)) * 16 + l15) * 128 +   \
                    ((((kk) * 64 + lhi * 16)) ^ swz_rd)))
#define RD_B(nh, ni, kk)                                                     \
  (*(const bf16x8*)(Bb + (wc * 64 + ((nh) * 2 + (ni)) * 16 + l15) * 128 +    \
                    ((((kk) * 64 + lhi * 16)) ^ swz_rd)))

#define LD_A(mh)                                                             \
  { _Pragma("unroll") for (int mi = 0; mi < 4; ++mi)                         \
      _Pragma("unroll") for (int kk = 0; kk < 2; ++kk)                       \
        a[mi][kk] = RD_A(mh, mi, kk); }
#define LD_B(nh)                                                             \
  { _Pragma("unroll") for (int ni = 0; ni < 2; ++ni)                         \
      _Pragma("unroll") for (int kk = 0; kk < 2; ++kk)                       \
        bfr[nh][ni][kk] = RD_B(nh, ni, kk); }

// operand-swapped: D row-side = B(o), col-side(l&15) = A(m)
#define MM(mh, nh)                                                           \
  do {                                                                       \
    _Pragma("unroll") for (int mi = 0; mi < 4; ++mi)                         \
      _Pragma("unroll") for (int ni = 0; ni < 2; ++ni)                       \
        _Pragma("unroll") for (int kk = 0; kk < 2; ++kk)                     \
          acc[(mh) * 4 + mi][(nh) * 2 + ni] =                                \
              __builtin_amdgcn_mfma_f32_16x16x32_bf16(                       \
                  bfr[nh][ni][kk], a[mi][kk],                                \
                  acc[(mh) * 4 + mi][(nh) * 2 + ni], 0, 0, 0);               \
  } while (0)

// steady virtual tile: reads tile tt; stages B(tt+1) ph1/2, A(tt+2) ph3/4
#define STEADY(tt)                                                           \
  {                                                                          \
    const char* Ab = lds + ((tt) & 1) * LDS_TILE;                            \
    const char* Bb = Ab + 32768;                                             \
    char* dB = lds + (((tt) + 1) & 1) * LDS_TILE;                            \
    char* dA = lds + ((tt) & 1) * LDS_TILE;                                  \
    const char* WsB = ((((tt) + 1) >> 4) ? Ws1 : Ws0);                       \
    const int ktB = ((tt) + 1) & 15, ktA = ((tt) + 2) & 15;                  \
    LD_A(0); LD_B(0);                                                        \
    STG_B(0, ktB, dB, WsB); STG_B(1, ktB, dB, WsB);                          \
    BAR; LGKM0; SCHB; PRIO(1); MM(0, 0); PRIO(0); SCHB; BAR;                 \
    LD_B(1);                                                                 \
    STG_B(2, ktB, dB, WsB); STG_B(3, ktB, dB, WsB);                          \
    BAR; LGKM0; SCHB; PRIO(1); MM(0, 1); PRIO(0); SCHB; BAR;                 \
    LD_A(1);                                                                 \
    STG_A(0, ktA, dA); STG_A(2, ktA, dA);                                    \
    BAR; LGKM0; SCHB; PRIO(1); MM(1, 0); PRIO(0); SCHB; BAR;                 \
    STG_A(1, ktA, dA); STG_A(3, ktA, dA);                                    \
    BAR; LGKM0; SCHB; PRIO(1); MM(1, 1); PRIO(0); SCHB;                      \
    VM(4); BAR;                                                              \
  }

// epilogue for pair p: lane holds 4 consecutive o -> dwordx4 stores
#define EPI(p)                                                               \
  {                                                                          \
    const int ob = wc * 64 + lhi * 4;                                        \
    _Pragma("unroll") for (int on = 0; on < 4; ++on) {                       \
      f32x4 dv = *(const f32x4*)(dtab + (p) * 256 + ob + on * 16);           \
      _Pragma("unroll") for (int am = 0; am < 8; ++am) {                     \
        const int m = m0 + wr * 128 + am * 16 + l15;                         \
        f32x4 v;                                                             \
        _Pragma("unroll") for (int j = 0; j < 4; ++j)                        \
          v[j] = acc[am][on][j] * dv[j];                                     \
        *(f32x4*)(out + (size_t)m * 1024 + n0base + (p) * 256 + ob +         \
                  on * 16) = v;                                              \
      }                                                                      \
    }                                                                        \
  }

__global__ __launch_bounds__(512, 1) void gemmp_kernel(
    const unsigned short* __restrict__ X, const unsigned short* __restrict__ WT,
    const float* __restrict__ dmod, float* __restrict__ out) {
  extern __shared__ char lds[];
  float* dtab = (float*)(lds + 2 * LDS_TILE);  // 2KB: d for both pairs

  const int tid = threadIdx.x;
  const int bid = blockIdx.x;                  // 0..255
  const int wg = (bid & 7) * 32 + (bid >> 3);  // bijective XCD swizzle
  const int bm = wg >> 1;                      // 0..127
  const int pairp = wg & 1;                    // bn pair {2p, 2p+1}
  const int m0 = bm * 256;
  const int n0base = pairp * 512;
  const int b = m0 >> 10;

  const int w = tid >> 6, l = tid & 63;
  const int wr = w >> 2, wc = w & 3;  // 2M x 4N waves
  const int l15 = l & 15, lhi = l >> 4;
  const int swz_rd = (l15 & 7) << 4;

  // staging: LDS written linearly; SOURCE column pre-swizzled (rule #21)
  const int srow = tid >> 3;
  const int scb = ((tid & 7) << 4) ^ ((srow & 7) << 4);
  const char* Xs = (const char*)X + (size_t)(m0 + srow) * 2048 + scb;
  const char* Ws0 = (const char*)WT + (size_t)(n0base + srow) * 2048 + scb;
  const char* Ws1 = Ws0 + (size_t)256 * 2048;
  const int sldso = tid * 16;

  f32x4 acc[8][4] = {};
  bf16x8 a[4][2], bfr[2][2][2];

  char* buf0 = lds;
  char* buf1 = lds + LDS_TILE;

  // ---- prologue: d table (clean VMEM before staging), then fill pipe ----
  dtab[tid] = dmod[b * 1024 + n0base + tid];  // tid = p*256 + c
  __syncthreads();

  STG_A(0, 0, buf0); STG_A(2, 0, buf0); STG_A(1, 0, buf0); STG_A(3, 0, buf0);
  STG_B(0, 0, buf0, Ws0); STG_B(1, 0, buf0, Ws0);
  STG_B(2, 0, buf0, Ws0); STG_B(3, 0, buf0, Ws0);
  STG_A(0, 1, buf1); STG_A(2, 1, buf1); STG_A(1, 1, buf1); STG_A(3, 1, buf1);
  VM(4);  // A(0)+B(0) done; A(1)x4 in flight
  BAR;

  // ---- pair 1: virtual tiles 0..15 ----
  for (int tt = 0; tt < 16; ++tt) STEADY(tt);

  EPI(0);
#pragma unroll
  for (int am = 0; am < 8; ++am)
#pragma unroll
    for (int on = 0; on < 4; ++on) acc[am][on] = (f32x4){0.f, 0.f, 0.f, 0.f};

  // ---- pair 2: virtual tiles 16..29 steady ----
  for (int tt = 16; tt < 30; ++tt) STEADY(tt);

  // tile 30: stage B(31) only; full drain at end
  {
    const char* Ab = lds + (30 & 1) * LDS_TILE;
    const char* Bb = Ab + 32768;
    char* dB = lds + (31 & 1) * LDS_TILE;
    LD_A(0); LD_B(0);
    STG_B(0, 15, dB, Ws1); STG_B(1, 15, dB, Ws1);
    BAR; LGKM0; SCHB; PRIO(1); MM(0, 0); PRIO(0); SCHB; BAR;
    LD_B(1);
    STG_B(2, 15, dB, Ws1); STG_B(3, 15, dB, Ws1);
    BAR; LGKM0; SCHB; PRIO(1); MM(0, 1); PRIO(0); SCHB; BAR;
    LD_A(1);
    BAR; LGKM0; SCHB; PRIO(1); MM(1, 0); PRIO(0); SCHB; BAR;
    BAR; LGKM0; SCHB; PRIO(1); MM(1, 1); PRIO(0); SCHB;
    VM(0); BAR;
  }

  // tile 31: bare compute
  {
    const char* Ab = lds + (31 & 1) * LDS_TILE;
    const char* Bb = Ab + 32768;
    LD_A(0); LD_B(0);
    BAR; LGKM0; SCHB; PRIO(1); MM(0, 0); PRIO(0); SCHB; BAR;
    LD_B(1);
    BAR; LGKM0; SCHB; PRIO(1); MM(0, 1); PRIO(0); SCHB; BAR;
    LD_A(1);
    BAR; LGKM0; SCHB; PRIO(1); MM(1, 0); PRIO(0); SCHB; BAR;
    BAR; LGKM0; SCHB; PRIO(1); MM(1, 1); PRIO(0); SCHB;
  }

  EPI(1);
}

// ---------------------------------------------------------------------------
extern "C" void kernel_launch(void* const* d_in, const int* in_sizes, int n_in,
                              void* d_out, int out_size, void* d_ws, size_t ws_size,
                              hipStream_t stream) {
  const float* Efou = (const float*)d_in[0];  // 32*1024*1024 fp32
  const float* y    = (const float*)d_in[1];  // 32*1024 fp32
  const float* W    = (const float*)d_in[2];  // 1024*1024 fp32
  float* out = (float*)d_out;

  unsigned short* X  = (unsigned short*)d_ws;               // 64 MB bf16
  unsigned short* WT = X + (size_t)32768 * 1024;            // 2 MB bf16
  float* dmod        = (float*)(WT + (size_t)1024 * 1024);  // 128 KB fp32
  float* dpart       = dmod + 32768;                        // 4 MB fp32

  hipFuncSetAttribute((const void*)gemmp_kernel,
                      hipFuncAttributeMaxDynamicSharedMemorySize, 133120);

  dcalc_a_kernel<<<dim3(4, 32), 256, 0, stream>>>(y, W, dpart);
  dcalc_b_kernel<<<128, 256, 0, stream>>>(dpart, dmod);
  wconv_kernel<<<dim3(32, 32), dim3(32, 8), 0, stream>>>(W, WT);
  xconv_kernel<<<2048, 256, 0, stream>>>((const float4*)Efou, y, X);
  gemmp_kernel<<<256, 512, 133120, stream>>>(X, WT, dmod, out);
}